// Round 6
// baseline (739.914 us; speedup 1.0000x reference)
//
#include <hip/hip_runtime.h>
#include <stdint.h>

#define N_K   10000
#define CIN   3
#define SEQ   1000
#define KM    11
#define NCLS  1024   // class key = (d-1)*4 + padbits ; d <= 166 -> key < 668
#define MAXQ  3400   // >= 10000/4 + NCLS

typedef _Float16 h2 __attribute__((ext_vector_type(2)));

// ---- workspace layout (int units) ------------------------------------------
// [0..15] per-batch queue counters, [16] Qtot
#define WS_QUADS_OFF   64
#define WS_SORT_OFF    (WS_QUADS_OFF + 2*(MAXQ+2))
#define WS_QDIL_OFF    (WS_SORT_OFF + N_K)
#define WS_QSPAN_OFF   (WS_QDIL_OFF + MAXQ + 4)
#define WS_QMETA_OFF   (WS_QSPAN_OFF + 2*(MAXQ+2))
#define WS_QBIAS_OFF   (WS_QMETA_OFF + 4*(MAXQ+2))
#define WS_QJ_OFF      (WS_QBIAS_OFF + 4*(MAXQ+2))
#define WS_QW_OFF      (WS_QJ_OFF + 4*(MAXQ+2))     // 68 u32 per quad

// ---------------- prep: class-sort, quad build, weight pre-pack --------------
__global__ __launch_bounds__(1024) void prep_kernel(
    const float* __restrict__ w, const float* __restrict__ bias,
    const int* __restrict__ dil, const int* __restrict__ start,
    const int* __restrict__ out_len, const int* __restrict__ pad_max_p,
    int* __restrict__ ws) {
  __shared__ int sA[NCLS];
  __shared__ int sB[NCLS];
  const int tid = threadIdx.x;
  const int pm = pad_max_p[0];

  int2* quads   = (int2*)(ws + WS_QUADS_OFF);
  int*  sortedj = ws + WS_SORT_OFF;
  int*  qdil    = ws + WS_QDIL_OFF;
  int2* qspan   = (int2*)(ws + WS_QSPAN_OFF);
  int4* qmeta   = (int4*)(ws + WS_QMETA_OFF);
  float4* qbias = (float4*)(ws + WS_QBIAS_OFF);
  int4* qjv     = (int4*)(ws + WS_QJ_OFF);
  unsigned* qw  = (unsigned*)(ws + WS_QW_OFF);

  // 1. class histogram
  sA[tid] = 0;
  __syncthreads();
  for (int j = tid; j < N_K; j += 1024) {
    int d = dil[j];
    int pads = pm - start[j];
    int key = (d - 1) * 4 + (pads > 0 ? 2 : 0) + (2 * pads > 7 * d ? 1 : 0);
    atomicAdd(&sA[min(key, NCLS - 1)], 1);
  }
  __syncthreads();
  // 2. inclusive scan (hazard-free Hillis-Steele)
  for (int off = 1; off < NCLS; off <<= 1) {
    int v = (tid >= off) ? sA[tid - off] : 0;
    __syncthreads();
    sA[tid] += v;
    __syncthreads();
  }
  sB[tid] = tid ? sA[tid - 1] : 0;
  __syncthreads();
  // 3. scatter j -> sortedj (class-grouped)
  for (int j = tid; j < N_K; j += 1024) {
    int d = dil[j];
    int pads = pm - start[j];
    int key = (d - 1) * 4 + (pads > 0 ? 2 : 0) + (2 * pads > 7 * d ? 1 : 0);
    int pos = atomicAdd(&sB[min(key, NCLS - 1)], 1);
    sortedj[pos] = j;
  }
  __syncthreads();
  // 4. per-class quad counts -> scan -> emit quads
  const int n_c = sA[tid] - (tid ? sA[tid - 1] : 0);
  const int cstart = sA[tid] - n_c;
  const int nq_c = (n_c + 3) >> 2;
  sB[tid] = nq_c;
  __syncthreads();
  for (int off = 1; off < NCLS; off <<= 1) {
    int v = (tid >= off) ? sB[tid - off] : 0;
    __syncthreads();
    sB[tid] += v;
    __syncthreads();
  }
  const int qstart = sB[tid] - nq_c;
  for (int u = 0; u < nq_c; ++u)
    quads[qstart + u] = make_int2(cstart + 4 * u, cstart + n_c - 1);
  __syncthreads();
  const int Qtot = sB[NCLS - 1];
  if (tid == 0) {
    ws[16] = Qtot;
    for (int i = 0; i < 16; ++i) ws[i] = 0;
  }
  __syncthreads();
  // 5. pack per-quad data
  for (int q = tid; q < Qtot; q += 1024) {
    int2 qr = quads[q];
    int jm[4];
#pragma unroll
    for (int m = 0; m < 4; ++m) jm[m] = sortedj[min(qr.x + m, qr.y)];
    qdil[q] = dil[jm[0]];
    int tlo = 0x7fffffff, thi = 0;
    int4 meta; float4 bv; int4 jv;
    int* mp = (int*)&meta; float* bp = (float*)&bv; int* jp = (int*)&jv;
#pragma unroll
    for (int m = 0; m < 4; ++m) {
      int smv = start[jm[m]];
      int ol = out_len[jm[m]];
      tlo = min(tlo, smv);
      thi = max(thi, smv + ol);
      mp[m] = (smv << 16) | ol;
      bp[m] = bias[jm[m]];
      jp[m] = jm[m];
    }
    qspan[q] = make_int2(tlo, thi);
    qmeta[q] = meta;
    qbias[q] = bv;
    qjv[q] = jv;
    unsigned* qq = qw + (size_t)q * 68;
#pragma unroll
    for (int m = 0; m < 4; ++m) {
      const float* wj = w + (size_t)jm[m] * (CIN * KM);
#pragma unroll
      for (int k = 0; k < KM; ++k) {
        h2 a;
        a.x = (_Float16)wj[k];
        a.y = (_Float16)wj[KM + k];
        qq[m * KM + k] = __builtin_bit_cast(unsigned, a);
      }
    }
#pragma unroll
    for (int p = 0; p < 2; ++p) {
      const float* w0 = w + (size_t)jm[2 * p] * (CIN * KM) + 2 * KM;
      const float* w1 = w + (size_t)jm[2 * p + 1] * (CIN * KM) + 2 * KM;
#pragma unroll
      for (int k = 0; k < KM; ++k) {
        h2 a;
        a.x = (_Float16)w0[k];
        a.y = (_Float16)w1[k];
        qq[44 + p * KM + k] = __builtin_bit_cast(unsigned, a);
      }
    }
    qq[66] = 0; qq[67] = 0;
  }
}

// ---------------- main: persistent; ONE quad per wave ------------------------
// All per-quad state is wave-uniform and forced into SGPRs via readfirstlane
// (v_dot2_f32_f16 reads one scalar operand). Lanes = 64 consecutive tau ->
// stride-1 b64 LDS reads (conflict-free, verified R4). Wave-uniform trip
// count -> zero divergence. Ticket loop is bounded (<= Q+1 pulls/wave).
__global__ __launch_bounds__(256) void rocket_kernel(
    const float* __restrict__ x, const int* __restrict__ pad_max_p,
    int* __restrict__ ws, float* __restrict__ out) {
  __shared__ __align__(16) unsigned long long xs[4 * 1002];

  const int tid = threadIdx.x;
  const int wv = tid >> 6;
  const int lane = tid & 63;
  const int bg = blockIdx.x & 3;
  const int b = bg * 4 + wv;

  // stage 4 batches, packed (c0,c1|c2,0) fp16 per position; sentinels 0/1001
  for (int lbb = 0; lbb < 4; ++lbb) {
    const float* xb = x + (size_t)(bg * 4 + lbb) * (CIN * SEQ);
    for (int pos = tid; pos < SEQ; pos += 256) {
      float a0 = xb[pos];
      float a1 = xb[SEQ + pos];
      float a2 = xb[2 * SEQ + pos];
      unsigned u0 = (unsigned)__builtin_bit_cast(unsigned short, (_Float16)a0);
      unsigned u1 = (unsigned)__builtin_bit_cast(unsigned short, (_Float16)a1);
      unsigned u2 = (unsigned)__builtin_bit_cast(unsigned short, (_Float16)a2);
      xs[lbb * 1002 + 1 + pos] =
          (unsigned long long)(u0 | (u1 << 16)) | ((unsigned long long)u2 << 32);
    }
  }
  if (tid < 8) xs[(tid >> 1) * 1002 + (tid & 1) * 1001] = 0ULL;
  __syncthreads();

  const int pm = pad_max_p[0];
  const int Q = __builtin_amdgcn_readfirstlane(ws[16]);
  int* ctr = ws;
  const int* qdil = ws + WS_QDIL_OFF;
  const int2* qspan = (const int2*)(ws + WS_QSPAN_OFF);
  const int4* qmeta = (const int4*)(ws + WS_QMETA_OFF);
  const float4* qbias = (const float4*)(ws + WS_QBIAS_OFF);
  const int4* qjv = (const int4*)(ws + WS_QJ_OFF);
  const unsigned* qw = (const unsigned*)(ws + WS_QW_OFF);

  const unsigned long long* xbase = xs + wv * 1002;

  for (int pull = 0; pull <= Q; ++pull) {
    int o = 0;
    if (lane == 0) o = atomicAdd(&ctr[b], 1);
    o = __builtin_amdgcn_readfirstlane(o);
    if (o >= Q) break;
    const int q = o;

    const int d = __builtin_amdgcn_readfirstlane(qdil[q]);
    const int2 spanv = qspan[q];
    const int span_lo = __builtin_amdgcn_readfirstlane(spanv.x);
    const int span_hi = __builtin_amdgcn_readfirstlane(spanv.y);
    const int4 meta = qmeta[q];
    const float4 bv = qbias[q];
    const int4 jv = qjv[q];

    // wave-uniform weight words -> force SGPRs
    unsigned W[66];
    {
      const unsigned* wp = qw + (size_t)q * 68;
#pragma unroll
      for (int i = 0; i < 66; ++i)
        W[i] = (unsigned)__builtin_amdgcn_readfirstlane((int)wp[i]);
    }
    int sm[4], olm[4];
    float bb[4];
    {
      const int* mp = (const int*)&meta;
      const float* bp = (const float*)&bv;
#pragma unroll
      for (int m = 0; m < 4; ++m) {
        int mw = __builtin_amdgcn_readfirstlane(mp[m]);
        sm[m] = mw >> 16;
        olm[m] = mw & 0xffff;
        bb[m] = __builtin_bit_cast(float, __builtin_amdgcn_readfirstlane(
                    __builtin_bit_cast(int, bp[m])));
      }
    }

    const int nIter = (span_hi - span_lo + 63) >> 6;  // wave-uniform
    int t = span_lo + lane;
    int pb = 1 + t - pm;  // LDS slot of tap 0 (slot = 1 + position)

    float mx[4] = {-3.0e38f, -3.0e38f, -3.0e38f, -3.0e38f};
    int cnt[4] = {0, 0, 0, 0};

#pragma unroll 1
    for (int i = 0; i < nIter; ++i) {
      float a0[4] = {0.f, 0.f, 0.f, 0.f};
      float a1[4] = {0.f, 0.f, 0.f, 0.f};
      int addr = pb;
#pragma unroll
      for (int k = 0; k < KM; ++k) {
        int qq = min(max(addr, 0), 1001);       // v_med3; sentinels absorb OOB
        unsigned long long v = xbase[qq];       // ds_read_b64, stride-1
        unsigned lo32 = (unsigned)v;
        unsigned hi32 = (unsigned)(v >> 32);
        h2 xl = __builtin_bit_cast(h2, lo32);          // (c0,c1)
        h2 xhl = __builtin_bit_cast(h2, hi32);         // (c2,0)
        h2 xhh = __builtin_bit_cast(h2, hi32 << 16);   // (0,c2)
        a0[0] = __builtin_amdgcn_fdot2(xl, __builtin_bit_cast(h2, W[0 * KM + k]), a0[0], false);
        a0[1] = __builtin_amdgcn_fdot2(xl, __builtin_bit_cast(h2, W[1 * KM + k]), a0[1], false);
        a0[2] = __builtin_amdgcn_fdot2(xl, __builtin_bit_cast(h2, W[2 * KM + k]), a0[2], false);
        a0[3] = __builtin_amdgcn_fdot2(xl, __builtin_bit_cast(h2, W[3 * KM + k]), a0[3], false);
        a1[0] = __builtin_amdgcn_fdot2(xhl, __builtin_bit_cast(h2, W[44 + k]), a1[0], false);
        a1[1] = __builtin_amdgcn_fdot2(xhh, __builtin_bit_cast(h2, W[44 + k]), a1[1], false);
        a1[2] = __builtin_amdgcn_fdot2(xhl, __builtin_bit_cast(h2, W[55 + k]), a1[2], false);
        a1[3] = __builtin_amdgcn_fdot2(xhh, __builtin_bit_cast(h2, W[55 + k]), a1[3], false);
        addr += d;
      }
#pragma unroll
      for (int m = 0; m < 4; ++m) {
        float val = a0[m] + a1[m];               // bias folded in at the end
        bool in = (unsigned)(t - sm[m]) < (unsigned)olm[m];
        mx[m] = fmaxf(mx[m], in ? val : -3.0e38f);
        cnt[m] += (in && val > -bb[m]) ? 1 : 0;  // val+bb > 0
      }
      t += 64;
      pb += 64;
    }

    // full-wave reduction over 64 tau-lanes
#pragma unroll
    for (int m = 0; m < 4; ++m) {
#pragma unroll
      for (int off = 1; off < 64; off <<= 1) {
        mx[m] = fmaxf(mx[m], __shfl_xor(mx[m], off));
        cnt[m] += __shfl_xor(cnt[m], off);
      }
    }
    if (lane == 0) {
      const int* jp = (const int*)&jv;
#pragma unroll
      for (int m = 0; m < 4; ++m) {
        float2 r;
        r.x = mx[m] + bb[m];
        r.y = (float)cnt[m] / (float)olm[m];
        *(float2*)(out + (size_t)b * (2 * N_K) + 2 * jp[m]) = r;
      }
    }
  }
}

extern "C" void kernel_launch(void* const* d_in, const int* in_sizes, int n_in,
                              void* d_out, int out_size, void* d_ws, size_t ws_size,
                              hipStream_t stream) {
  const float* x       = (const float*)d_in[0];
  const float* weight  = (const float*)d_in[1];
  const float* bias    = (const float*)d_in[2];
  const int*   dil     = (const int*)d_in[3];
  const int*   start   = (const int*)d_in[4];
  const int*   out_len = (const int*)d_in[5];
  const int*   pad_max = (const int*)d_in[6];
  (void)in_sizes; (void)n_in; (void)out_size; (void)ws_size;

  int* ws = (int*)d_ws;

  prep_kernel<<<1, 1024, 0, stream>>>(weight, bias, dil, start, out_len,
                                      pad_max, ws);

  rocket_kernel<<<1024, 256, 0, stream>>>(x, pad_max, ws, (float*)d_out);
}

// Round 7
// 465.249 us; speedup vs baseline: 1.5904x; 1.5904x over previous
//
#include <hip/hip_runtime.h>
#include <stdint.h>

#define N_K   10000
#define CIN   3
#define SEQ   1000
#define KM    11
#define NCLS  1024   // class key = (d-1)*4 + padbits ; d <= 166 -> key < 668
#define MAXQ  3400   // >= 10000/4 + NCLS

typedef _Float16 h2 __attribute__((ext_vector_type(2)));

// ---- workspace layout (int units) ------------------------------------------
// [16] Qtot
#define WS_QUADS_OFF   64
#define WS_SORT_OFF    (WS_QUADS_OFF + 2*(MAXQ+2))
#define WS_QDIL_OFF    (WS_SORT_OFF + N_K)
#define WS_QSPAN_OFF   (WS_QDIL_OFF + MAXQ + 4)
#define WS_QMETA_OFF   (WS_QSPAN_OFF + 2*(MAXQ+2))
#define WS_QBIAS_OFF   (WS_QMETA_OFF + 4*(MAXQ+2))
#define WS_QJ_OFF      (WS_QBIAS_OFF + 4*(MAXQ+2))
#define WS_QW_OFF      (WS_QJ_OFF + 4*(MAXQ+2))     // 68 u32 per quad

// ---------------- prep: class-sort, quad build, weight pre-pack --------------
__global__ __launch_bounds__(1024) void prep_kernel(
    const float* __restrict__ w, const float* __restrict__ bias,
    const int* __restrict__ dil, const int* __restrict__ start,
    const int* __restrict__ out_len, const int* __restrict__ pad_max_p,
    int* __restrict__ ws) {
  __shared__ int sA[NCLS];
  __shared__ int sB[NCLS];
  const int tid = threadIdx.x;
  const int pm = pad_max_p[0];

  int2* quads   = (int2*)(ws + WS_QUADS_OFF);
  int*  sortedj = ws + WS_SORT_OFF;
  int*  qdil    = ws + WS_QDIL_OFF;
  int2* qspan   = (int2*)(ws + WS_QSPAN_OFF);
  int4* qmeta   = (int4*)(ws + WS_QMETA_OFF);
  float4* qbias = (float4*)(ws + WS_QBIAS_OFF);
  int4* qjv     = (int4*)(ws + WS_QJ_OFF);
  unsigned* qw  = (unsigned*)(ws + WS_QW_OFF);

  // 1. class histogram
  sA[tid] = 0;
  __syncthreads();
  for (int j = tid; j < N_K; j += 1024) {
    int d = dil[j];
    int pads = pm - start[j];
    int key = (d - 1) * 4 + (pads > 0 ? 2 : 0) + (2 * pads > 7 * d ? 1 : 0);
    atomicAdd(&sA[min(key, NCLS - 1)], 1);
  }
  __syncthreads();
  // 2. inclusive scan (hazard-free Hillis-Steele)
  for (int off = 1; off < NCLS; off <<= 1) {
    int v = (tid >= off) ? sA[tid - off] : 0;
    __syncthreads();
    sA[tid] += v;
    __syncthreads();
  }
  sB[tid] = tid ? sA[tid - 1] : 0;
  __syncthreads();
  // 3. scatter j -> sortedj (class-grouped; ascending d ~ descending span)
  for (int j = tid; j < N_K; j += 1024) {
    int d = dil[j];
    int pads = pm - start[j];
    int key = (d - 1) * 4 + (pads > 0 ? 2 : 0) + (2 * pads > 7 * d ? 1 : 0);
    int pos = atomicAdd(&sB[min(key, NCLS - 1)], 1);
    sortedj[pos] = j;
  }
  __syncthreads();
  // 4. per-class quad counts -> scan -> emit quads
  const int n_c = sA[tid] - (tid ? sA[tid - 1] : 0);
  const int cstart = sA[tid] - n_c;
  const int nq_c = (n_c + 3) >> 2;
  sB[tid] = nq_c;
  __syncthreads();
  for (int off = 1; off < NCLS; off <<= 1) {
    int v = (tid >= off) ? sB[tid - off] : 0;
    __syncthreads();
    sB[tid] += v;
    __syncthreads();
  }
  const int qstart = sB[tid] - nq_c;
  for (int u = 0; u < nq_c; ++u)
    quads[qstart + u] = make_int2(cstart + 4 * u, cstart + n_c - 1);
  __syncthreads();
  const int Qtot = sB[NCLS - 1];
  if (tid == 0) ws[16] = Qtot;
  __syncthreads();
  // 5. pack per-quad data
  for (int q = tid; q < Qtot; q += 1024) {
    int2 qr = quads[q];
    int jm[4];
#pragma unroll
    for (int m = 0; m < 4; ++m) jm[m] = sortedj[min(qr.x + m, qr.y)];
    qdil[q] = dil[jm[0]];
    int tlo = 0x7fffffff, thi = 0;
    int4 meta; float4 bv; int4 jv;
    int* mp = (int*)&meta; float* bp = (float*)&bv; int* jp = (int*)&jv;
#pragma unroll
    for (int m = 0; m < 4; ++m) {
      int smv = start[jm[m]];
      int ol = out_len[jm[m]];
      tlo = min(tlo, smv);
      thi = max(thi, smv + ol);
      mp[m] = (smv << 16) | ol;
      bp[m] = bias[jm[m]];
      jp[m] = jm[m];
    }
    qspan[q] = make_int2(tlo, thi);
    qmeta[q] = meta;
    qbias[q] = bv;
    qjv[q] = jv;
    // weights: W[m*11+k] = (w_c0, w_c1); W[44+m*6+kp] = (w_c2[2kp], w_c2[2kp+1]),
    // kp=5 -> (w_c2[10], 0)
    unsigned* qq = qw + (size_t)q * 68;
#pragma unroll
    for (int m = 0; m < 4; ++m) {
      const float* wj = w + (size_t)jm[m] * (CIN * KM);
#pragma unroll
      for (int k = 0; k < KM; ++k) {
        h2 a;
        a.x = (_Float16)wj[k];
        a.y = (_Float16)wj[KM + k];
        qq[m * KM + k] = __builtin_bit_cast(unsigned, a);
      }
      const float* w2 = wj + 2 * KM;
#pragma unroll
      for (int kp = 0; kp < 6; ++kp) {
        h2 a;
        a.x = (_Float16)w2[2 * kp];
        a.y = (kp < 5) ? (_Float16)w2[2 * kp + 1] : (_Float16)0.f;
        qq[44 + m * 6 + kp] = __builtin_bit_cast(unsigned, a);
      }
    }
  }
}

// ---------------- main -------------------------------------------------------
// block = 4 waves; wave <-> one batch. Wave = 2 quad-groups x 32 consecutive
// tau-lanes -> each ds_read_b64 is 2 runs of 32 consecutive u64 = bank-uniform,
// zero conflicts (verified R4/R6). Weights per-lane in VGPRs (R3: no spill at
// 80 VGPRs; R4/R6 proved any cap or SGPR plan spills). Static pair->block map.
__global__ __launch_bounds__(256) void rocket_kernel(
    const float* __restrict__ x, const int* __restrict__ pad_max_p,
    const int* __restrict__ ws, float* __restrict__ out) {
  __shared__ __align__(16) unsigned long long xs[4 * 1002];

  const int tid = threadIdx.x;
  const int wv = tid >> 6;          // wave = batch within group
  const int lane = tid & 63;
  const int g = lane >> 5;          // quad-group within pair
  const int s = lane & 31;          // tau slot (consecutive)
  const int bg = blockIdx.x & 3;    // 4 batch groups of 4
  const int bp = blockIdx.x >> 2;   // pair-slot 0..255
  const int b = bg * 4 + wv;

  // stage 4 batches, packed (c0,c1|c2,0) fp16 per position; sentinels 0/1001
  for (int lbb = 0; lbb < 4; ++lbb) {
    const float* xb = x + (size_t)(bg * 4 + lbb) * (CIN * SEQ);
    for (int pos = tid; pos < SEQ; pos += 256) {
      float a0 = xb[pos];
      float a1 = xb[SEQ + pos];
      float a2 = xb[2 * SEQ + pos];
      unsigned u0 = (unsigned)__builtin_bit_cast(unsigned short, (_Float16)a0);
      unsigned u1 = (unsigned)__builtin_bit_cast(unsigned short, (_Float16)a1);
      unsigned u2 = (unsigned)__builtin_bit_cast(unsigned short, (_Float16)a2);
      xs[lbb * 1002 + 1 + pos] =
          (unsigned long long)(u0 | (u1 << 16)) | ((unsigned long long)u2 << 32);
    }
  }
  if (tid < 8) xs[(tid >> 1) * 1002 + (tid & 1) * 1001] = 0ULL;
  __syncthreads();

  const int pm = pad_max_p[0];
  const int Q = __builtin_amdgcn_readfirstlane(ws[16]);
  const int NP = (Q + 1) >> 1;
  const int* qdil = ws + WS_QDIL_OFF;
  const int2* qspan = (const int2*)(ws + WS_QSPAN_OFF);
  const int4* qmeta = (const int4*)(ws + WS_QMETA_OFF);
  const float4* qbias = (const float4*)(ws + WS_QBIAS_OFF);
  const int4* qjv = (const int4*)(ws + WS_QJ_OFF);
  const unsigned* qw = (const unsigned*)(ws + WS_QW_OFF);

  const unsigned long long* xbase = xs + wv * 1002;

  for (int p = bp; p < NP; p += 256) {
    const int q = min(2 * p + g, Q - 1);

    const int d = qdil[q];
    const int d2 = d * 2;
    const int2 spanq = qspan[q];
    const int4 meta = qmeta[q];
    const float4 bv = qbias[q];
    const int4 jv = qjv[q];

    unsigned W[68];
    {
      const uint4* wp = (const uint4*)(qw + (size_t)q * 68);
#pragma unroll
      for (int i = 0; i < 17; ++i) {
        uint4 u = wp[i];
        W[4 * i + 0] = u.x;
        W[4 * i + 1] = u.y;
        W[4 * i + 2] = u.z;
        W[4 * i + 3] = u.w;
      }
    }
    int sm[4], olm[4];
    float bb[4], nb[4];
    {
      const int* mp = (const int*)&meta;
      const float* bp2 = (const float*)&bv;
#pragma unroll
      for (int m = 0; m < 4; ++m) {
        sm[m] = mp[m] >> 16;
        olm[m] = mp[m] & 0xffff;
        bb[m] = bp2[m];
        nb[m] = -bb[m];
      }
    }

    // pair-uniform tau range (union of the two quads' spans)
    int t0 = min(spanq.x, __shfl_xor(spanq.x, 32));
    int t1 = max(spanq.y, __shfl_xor(spanq.y, 32));
    t0 = __builtin_amdgcn_readfirstlane(t0);
    t1 = __builtin_amdgcn_readfirstlane(t1);
    const int nIter = (t1 - t0 + 31) >> 5;

    int t = t0 + s;
    int pb = 1 + t - pm;  // LDS slot of tap 0 (slot = 1 + position)

    float mx[4] = {-3.0e38f, -3.0e38f, -3.0e38f, -3.0e38f};
    int cnt[4] = {0, 0, 0, 0};

#pragma unroll 1
    for (int i = 0; i < nIter; ++i) {
      float a0[4] = {0.f, 0.f, 0.f, 0.f};
      float a1[4] = {0.f, 0.f, 0.f, 0.f};
      int addr = pb;
#pragma unroll
      for (int kp = 0; kp < 5; ++kp) {
        int aA = min(max(addr, 0), 1001);
        int aB = min(max(addr + d, 0), 1001);
        unsigned long long vA = xbase[aA];   // ds_read_b64, stride-1 runs
        unsigned long long vB = xbase[aB];
        addr += d2;
        unsigned loA = (unsigned)vA, hiA = (unsigned)(vA >> 32);
        unsigned loB = (unsigned)vB, hiB = (unsigned)(vB >> 32);
        h2 xA = __builtin_bit_cast(h2, loA);
        h2 xB = __builtin_bit_cast(h2, loB);
        // (c2_k, c2_{k+1}) from the two hi words
        h2 xP = __builtin_bit_cast(h2,
                  __builtin_amdgcn_perm(hiB, hiA, 0x05040100u));
#pragma unroll
        for (int m = 0; m < 4; ++m) {
          a0[m] = __builtin_amdgcn_fdot2(xA, __builtin_bit_cast(h2, W[m * KM + 2 * kp]), a0[m], false);
          a0[m] = __builtin_amdgcn_fdot2(xB, __builtin_bit_cast(h2, W[m * KM + 2 * kp + 1]), a0[m], false);
          a1[m] = __builtin_amdgcn_fdot2(xP, __builtin_bit_cast(h2, W[44 + m * 6 + kp]), a1[m], false);
        }
      }
      {  // tap 10: hi = (c2, 0); Wpair[5] = (w_c2[10], 0)
        int aL = min(max(addr, 0), 1001);
        unsigned long long vL = xbase[aL];
        unsigned loL = (unsigned)vL, hiL = (unsigned)(vL >> 32);
        h2 xL = __builtin_bit_cast(h2, loL);
        h2 xH = __builtin_bit_cast(h2, hiL);
#pragma unroll
        for (int m = 0; m < 4; ++m) {
          a0[m] = __builtin_amdgcn_fdot2(xL, __builtin_bit_cast(h2, W[m * KM + 10]), a0[m], false);
          a1[m] = __builtin_amdgcn_fdot2(xH, __builtin_bit_cast(h2, W[44 + m * 6 + 5]), a1[m], false);
        }
      }
#pragma unroll
      for (int m = 0; m < 4; ++m) {
        float val = a0[m] + a1[m];               // bias folded in at the end
        bool in = (unsigned)(t - sm[m]) < (unsigned)olm[m];
        mx[m] = fmaxf(mx[m], in ? val : -3.0e38f);
        cnt[m] += (in && val > nb[m]) ? 1 : 0;   // val + bb > 0
      }
      t += 32;
      pb += 32;
    }

    // reduce across the 32 tau-lanes of this quad-group
#pragma unroll
    for (int m = 0; m < 4; ++m) {
#pragma unroll
      for (int off = 1; off < 32; off <<= 1) {
        mx[m] = fmaxf(mx[m], __shfl_xor(mx[m], off));
        cnt[m] += __shfl_xor(cnt[m], off);
      }
    }
    if (s == 0) {
      const int* jp = (const int*)&jv;
#pragma unroll
      for (int m = 0; m < 4; ++m) {
        float2 r;
        r.x = mx[m] + bb[m];
        r.y = (float)cnt[m] / (float)olm[m];
        *(float2*)(out + (size_t)b * (2 * N_K) + 2 * jp[m]) = r;
      }
    }
  }
}

extern "C" void kernel_launch(void* const* d_in, const int* in_sizes, int n_in,
                              void* d_out, int out_size, void* d_ws, size_t ws_size,
                              hipStream_t stream) {
  const float* x       = (const float*)d_in[0];
  const float* weight  = (const float*)d_in[1];
  const float* bias    = (const float*)d_in[2];
  const int*   dil     = (const int*)d_in[3];
  const int*   start   = (const int*)d_in[4];
  const int*   out_len = (const int*)d_in[5];
  const int*   pad_max = (const int*)d_in[6];
  (void)in_sizes; (void)n_in; (void)out_size; (void)ws_size;

  int* ws = (int*)d_ws;

  prep_kernel<<<1, 1024, 0, stream>>>(weight, bias, dil, start, out_len,
                                      pad_max, ws);

  rocket_kernel<<<1024, 256, 0, stream>>>(x, pad_max, ws, (float*)d_out);
}

// Round 8
// 402.867 us; speedup vs baseline: 1.8366x; 1.1548x over previous
//
#include <hip/hip_runtime.h>
#include <stdint.h>

#define N_K   10000
#define CIN   3
#define SEQ   1000
#define KM    11
#define NCLS  1024   // class key = (d-1)*4 + padbits ; d <= 166 -> key < 668
#define MAXQ  3400   // >= 10000/4 + NCLS

typedef _Float16 h2 __attribute__((ext_vector_type(2)));

// ---- workspace layout (int units) ------------------------------------------
// [0..15] per-batch queue counters, [16] Qtot
#define WS_QUADS_OFF   64
#define WS_SORT_OFF    (WS_QUADS_OFF + 2*(MAXQ+2))
#define WS_QDIL_OFF    (WS_SORT_OFF + N_K)
#define WS_QSPAN_OFF   (WS_QDIL_OFF + MAXQ + 4)
#define WS_QMETA_OFF   (WS_QSPAN_OFF + 2*(MAXQ+2))
#define WS_QBIAS_OFF   (WS_QMETA_OFF + 4*(MAXQ+2))
#define WS_QJ_OFF      (WS_QBIAS_OFF + 4*(MAXQ+2))
#define WS_QW_OFF      (WS_QJ_OFF + 4*(MAXQ+2))     // 68 u32 per quad

// ---------------- build: class-sort + quad emission (1 block, light) ---------
__global__ __launch_bounds__(1024) void build_kernel(
    const int* __restrict__ dil, const int* __restrict__ start,
    const int* __restrict__ pad_max_p, int* __restrict__ ws) {
  __shared__ int sA[NCLS];
  __shared__ int sB[NCLS];
  const int tid = threadIdx.x;
  const int pm = pad_max_p[0];

  int2* quads  = (int2*)(ws + WS_QUADS_OFF);
  int* sortedj = ws + WS_SORT_OFF;

  // 1. class histogram
  sA[tid] = 0;
  __syncthreads();
  for (int j = tid; j < N_K; j += 1024) {
    int d = dil[j];
    int pads = pm - start[j];
    int key = (d - 1) * 4 + (pads > 0 ? 2 : 0) + (2 * pads > 7 * d ? 1 : 0);
    atomicAdd(&sA[min(key, NCLS - 1)], 1);
  }
  __syncthreads();
  // 2. inclusive scan (hazard-free)
  for (int off = 1; off < NCLS; off <<= 1) {
    int v = (tid >= off) ? sA[tid - off] : 0;
    __syncthreads();
    sA[tid] += v;
    __syncthreads();
  }
  sB[tid] = tid ? sA[tid - 1] : 0;
  __syncthreads();
  // 3. scatter j -> sortedj (class-grouped)
  for (int j = tid; j < N_K; j += 1024) {
    int d = dil[j];
    int pads = pm - start[j];
    int key = (d - 1) * 4 + (pads > 0 ? 2 : 0) + (2 * pads > 7 * d ? 1 : 0);
    int pos = atomicAdd(&sB[min(key, NCLS - 1)], 1);
    sortedj[pos] = j;
  }
  __syncthreads();
  // 4. per-class quad counts -> scan -> emit quads
  const int n_c = sA[tid] - (tid ? sA[tid - 1] : 0);
  const int cstart = sA[tid] - n_c;
  const int nq_c = (n_c + 3) >> 2;
  sB[tid] = nq_c;
  __syncthreads();
  for (int off = 1; off < NCLS; off <<= 1) {
    int v = (tid >= off) ? sB[tid - off] : 0;
    __syncthreads();
    sB[tid] += v;
    __syncthreads();
  }
  const int qstart = sB[tid] - nq_c;
  for (int u = 0; u < nq_c; ++u)
    quads[qstart + u] = make_int2(cstart + 4 * u, cstart + n_c - 1);
  __syncthreads();
  if (tid == 0) {
    ws[16] = sB[NCLS - 1];              // Qtot
    for (int i = 0; i < 16; ++i) ws[i] = 0;  // queue counters
  }
}

// ---------------- pack: per-(quad,member) meta + fp16 weight pack ------------
__global__ __launch_bounds__(256) void pack_kernel(
    const float* __restrict__ w, const float* __restrict__ bias,
    const int* __restrict__ dil, const int* __restrict__ start,
    const int* __restrict__ out_len, int* __restrict__ ws) {
  const int g = blockIdx.x * 256 + threadIdx.x;
  const int q = g >> 2;
  const int m = g & 3;
  const int Qtot = ws[16];
  if (q >= Qtot) return;

  const int2* quads = (const int2*)(ws + WS_QUADS_OFF);
  const int* sortedj = ws + WS_SORT_OFF;
  int* qdil = ws + WS_QDIL_OFF;
  int2* qspan = (int2*)(ws + WS_QSPAN_OFF);
  int* qmeta = ws + WS_QMETA_OFF;
  float* qbias = (float*)(ws + WS_QBIAS_OFF);
  int* qjv = ws + WS_QJ_OFF;
  unsigned* qw = (unsigned*)(ws + WS_QW_OFF);

  const int2 qr = quads[q];
  const int jm = sortedj[min(qr.x + m, qr.y)];

  const int smv = start[jm];
  const int ol = out_len[jm];
  qmeta[4 * q + m] = (smv << 16) | ol;
  qbias[4 * q + m] = bias[jm];
  qjv[4 * q + m] = jm;

  if (m == 0) {
    qdil[q] = dil[jm];
    int tlo = 0x7fffffff, thi = 0;
#pragma unroll
    for (int mm = 0; mm < 4; ++mm) {
      int jx = sortedj[min(qr.x + mm, qr.y)];
      int s2 = start[jx], o2 = out_len[jx];
      tlo = min(tlo, s2);
      thi = max(thi, s2 + o2);
    }
    qspan[q] = make_int2(tlo, thi);
  }

  // weights: W[m*11+k] = (w_c0,w_c1); W[44+m*6+kp] = (w_c2[2kp], w_c2[2kp+1]),
  // kp=5 -> (w_c2[10], 0)
  const float* wj = w + (size_t)jm * (CIN * KM);
  unsigned* qq = qw + (size_t)q * 68;
#pragma unroll
  for (int k = 0; k < KM; ++k) {
    h2 a;
    a.x = (_Float16)wj[k];
    a.y = (_Float16)wj[KM + k];
    qq[m * KM + k] = __builtin_bit_cast(unsigned, a);
  }
  const float* w2 = wj + 2 * KM;
#pragma unroll
  for (int kp = 0; kp < 6; ++kp) {
    h2 a;
    a.x = (_Float16)w2[2 * kp];
    a.y = (kp < 5) ? (_Float16)w2[2 * kp + 1] : (_Float16)0.f;
    qq[44 + m * 6 + kp] = __builtin_bit_cast(unsigned, a);
  }
}

// ---------------- main -------------------------------------------------------
// block = 4 waves; wave <-> one batch. Wave = 2 quad-groups x 32 consecutive
// tau-lanes (stride-1 b64 LDS = zero conflicts, verified R4/R6/R7). Weights
// per-lane in VGPRs (R3/R7: no spill at 80 VGPRs; any cap/SGPR plan spills).
// Dynamic per-batch ticket queue for load balance (R7's static map -> 22%
// occupancy was the limiter).
__global__ __launch_bounds__(256) void rocket_kernel(
    const float* __restrict__ x, const int* __restrict__ pad_max_p,
    int* __restrict__ ws, float* __restrict__ out) {
  __shared__ __align__(16) unsigned long long xs[4 * 1002];

  const int tid = threadIdx.x;
  const int wv = tid >> 6;          // wave = batch within group
  const int lane = tid & 63;
  const int g = lane >> 5;          // quad-group within pair
  const int s = lane & 31;          // tau slot (consecutive)
  const int bg = blockIdx.x & 3;    // 4 batch groups of 4
  const int b = bg * 4 + wv;

  // stage 4 batches, packed (c0,c1|c2,0) fp16 per position; sentinels 0/1001
  for (int lbb = 0; lbb < 4; ++lbb) {
    const float* xb = x + (size_t)(bg * 4 + lbb) * (CIN * SEQ);
    for (int pos = tid; pos < SEQ; pos += 256) {
      float a0 = xb[pos];
      float a1 = xb[SEQ + pos];
      float a2 = xb[2 * SEQ + pos];
      unsigned u0 = (unsigned)__builtin_bit_cast(unsigned short, (_Float16)a0);
      unsigned u1 = (unsigned)__builtin_bit_cast(unsigned short, (_Float16)a1);
      unsigned u2 = (unsigned)__builtin_bit_cast(unsigned short, (_Float16)a2);
      xs[lbb * 1002 + 1 + pos] =
          (unsigned long long)(u0 | (u1 << 16)) | ((unsigned long long)u2 << 32);
    }
  }
  if (tid < 8) xs[(tid >> 1) * 1002 + (tid & 1) * 1001] = 0ULL;
  __syncthreads();

  const int pm = pad_max_p[0];
  const int Q = __builtin_amdgcn_readfirstlane(ws[16]);
  const int NP = (Q + 1) >> 1;
  int* ctr = ws;
  const int* qdil = ws + WS_QDIL_OFF;
  const int2* qspan = (const int2*)(ws + WS_QSPAN_OFF);
  const int4* qmeta = (const int4*)(ws + WS_QMETA_OFF);
  const float4* qbias = (const float4*)(ws + WS_QBIAS_OFF);
  const int4* qjv = (const int4*)(ws + WS_QJ_OFF);
  const unsigned* qw = (const unsigned*)(ws + WS_QW_OFF);

  const unsigned long long* xbase = xs + wv * 1002;

  for (int pull = 0; pull <= NP; ++pull) {
    int o = 0;
    if (lane == 0) o = atomicAdd(&ctr[b], 1);
    o = __builtin_amdgcn_readfirstlane(o);
    if (o >= NP) break;
    const int q = min(2 * o + g, Q - 1);

    const int d = qdil[q];
    const int d2 = d * 2;
    const int2 spanq = qspan[q];
    const int4 meta = qmeta[q];
    const float4 bv = qbias[q];
    const int4 jv = qjv[q];

    unsigned W[68];
    {
      const uint4* wp = (const uint4*)(qw + (size_t)q * 68);
#pragma unroll
      for (int i = 0; i < 17; ++i) {
        uint4 u = wp[i];
        W[4 * i + 0] = u.x;
        W[4 * i + 1] = u.y;
        W[4 * i + 2] = u.z;
        W[4 * i + 3] = u.w;
      }
    }
    int sm[4], olm[4];
    float bb[4], nb[4];
    {
      const int* mp = (const int*)&meta;
      const float* bp2 = (const float*)&bv;
#pragma unroll
      for (int m = 0; m < 4; ++m) {
        sm[m] = mp[m] >> 16;
        olm[m] = mp[m] & 0xffff;
        bb[m] = bp2[m];
        nb[m] = -bb[m];
      }
    }

    // pair-uniform tau range (union of the two quads' spans)
    int t0 = min(spanq.x, __shfl_xor(spanq.x, 32));
    int t1 = max(spanq.y, __shfl_xor(spanq.y, 32));
    t0 = __builtin_amdgcn_readfirstlane(t0);
    t1 = __builtin_amdgcn_readfirstlane(t1);
    const int nIter = (t1 - t0 + 31) >> 5;

    int t = t0 + s;
    int pb = 1 + t - pm;  // LDS slot of tap 0 (slot = 1 + position)

    float mx[4] = {-3.0e38f, -3.0e38f, -3.0e38f, -3.0e38f};
    int cnt[4] = {0, 0, 0, 0};

#pragma unroll 1
    for (int i = 0; i < nIter; ++i) {
      float a0[4] = {0.f, 0.f, 0.f, 0.f};
      float a1[4] = {0.f, 0.f, 0.f, 0.f};
      int addr = pb;
#pragma unroll
      for (int kp = 0; kp < 5; ++kp) {
        int aA = min(max(addr, 0), 1001);
        int aB = min(max(addr + d, 0), 1001);
        unsigned long long vA = xbase[aA];   // ds_read_b64, stride-1 runs
        unsigned long long vB = xbase[aB];
        addr += d2;
        unsigned loA = (unsigned)vA, hiA = (unsigned)(vA >> 32);
        unsigned loB = (unsigned)vB, hiB = (unsigned)(vB >> 32);
        h2 xA = __builtin_bit_cast(h2, loA);
        h2 xB = __builtin_bit_cast(h2, loB);
        h2 xP = __builtin_bit_cast(h2,
                  __builtin_amdgcn_perm(hiB, hiA, 0x05040100u));  // (c2_k, c2_k+1)
#pragma unroll
        for (int m = 0; m < 4; ++m) {
          a0[m] = __builtin_amdgcn_fdot2(xA, __builtin_bit_cast(h2, W[m * KM + 2 * kp]), a0[m], false);
          a0[m] = __builtin_amdgcn_fdot2(xB, __builtin_bit_cast(h2, W[m * KM + 2 * kp + 1]), a0[m], false);
          a1[m] = __builtin_amdgcn_fdot2(xP, __builtin_bit_cast(h2, W[44 + m * 6 + kp]), a1[m], false);
        }
      }
      {  // tap 10: hi = (c2, 0); Wpair[5] = (w_c2[10], 0)
        int aL = min(max(addr, 0), 1001);
        unsigned long long vL = xbase[aL];
        unsigned loL = (unsigned)vL, hiL = (unsigned)(vL >> 32);
        h2 xL = __builtin_bit_cast(h2, loL);
        h2 xH = __builtin_bit_cast(h2, hiL);
#pragma unroll
        for (int m = 0; m < 4; ++m) {
          a0[m] = __builtin_amdgcn_fdot2(xL, __builtin_bit_cast(h2, W[m * KM + 10]), a0[m], false);
          a1[m] = __builtin_amdgcn_fdot2(xH, __builtin_bit_cast(h2, W[44 + m * 6 + 5]), a1[m], false);
        }
      }
#pragma unroll
      for (int m = 0; m < 4; ++m) {
        float val = a0[m] + a1[m];               // bias folded in at the end
        bool in = (unsigned)(t - sm[m]) < (unsigned)olm[m];
        mx[m] = fmaxf(mx[m], in ? val : -3.0e38f);
        cnt[m] += (in && val > nb[m]) ? 1 : 0;   // val + bb > 0
      }
      t += 32;
      pb += 32;
    }

    // reduce across the 32 tau-lanes of this quad-group
#pragma unroll
    for (int m = 0; m < 4; ++m) {
#pragma unroll
      for (int off = 1; off < 32; off <<= 1) {
        mx[m] = fmaxf(mx[m], __shfl_xor(mx[m], off));
        cnt[m] += __shfl_xor(cnt[m], off);
      }
    }
    if (s == 0) {
      const int* jp = (const int*)&jv;
#pragma unroll
      for (int m = 0; m < 4; ++m) {
        float2 r;
        r.x = mx[m] + bb[m];
        r.y = (float)cnt[m] / (float)olm[m];
        *(float2*)(out + (size_t)b * (2 * N_K) + 2 * jp[m]) = r;
      }
    }
  }
}

extern "C" void kernel_launch(void* const* d_in, const int* in_sizes, int n_in,
                              void* d_out, int out_size, void* d_ws, size_t ws_size,
                              hipStream_t stream) {
  const float* x       = (const float*)d_in[0];
  const float* weight  = (const float*)d_in[1];
  const float* bias    = (const float*)d_in[2];
  const int*   dil     = (const int*)d_in[3];
  const int*   start   = (const int*)d_in[4];
  const int*   out_len = (const int*)d_in[5];
  const int*   pad_max = (const int*)d_in[6];
  (void)in_sizes; (void)n_in; (void)out_size; (void)ws_size;

  int* ws = (int*)d_ws;

  build_kernel<<<1, 1024, 0, stream>>>(dil, start, pad_max, ws);
  pack_kernel<<<(MAXQ * 4 + 255) / 256, 256, 0, stream>>>(
      weight, bias, dil, start, out_len, ws);
  rocket_kernel<<<1280, 256, 0, stream>>>(x, pad_max, ws, (float*)d_out);
}